// Round 2
// baseline (770.995 us; speedup 1.0000x reference)
//
#include <hip/hip_runtime.h>

typedef unsigned short u16;
typedef __attribute__((ext_vector_type(8))) short bf16x8;
typedef __attribute__((ext_vector_type(4))) float f32x4;

__device__ inline u16 f2b(float f) {
  unsigned u = __float_as_uint(f);
  unsigned r = (u + 0x7fffu + ((u >> 16) & 1u)) >> 16;
  return (u16)r;
}

__device__ inline float wsum(float x) {
#pragma unroll
  for (int o = 32; o > 0; o >>= 1) x += __shfl_down(x, o);
  return x;
}
__device__ inline float wmax(float x) {
#pragma unroll
  for (int o = 32; o > 0; o >>= 1) x = fmaxf(x, __shfl_down(x, o));
  return x;
}

// ---------------- LayerNorm fp32 -> bf16 (one block per 1024-elem row) ----------------
__global__ __launch_bounds__(256) void ln_kernel(const float* __restrict__ x,
                                                 const float* __restrict__ g,
                                                 const float* __restrict__ bta,
                                                 u16* __restrict__ y) {
  long base = (long)blockIdx.x * 1024;
  int t = threadIdx.x;
  float4 raw = *(const float4*)(x + base + t * 4);
  float v[4] = {raw.x, raw.y, raw.z, raw.w};
  float s = 0.f, ss = 0.f;
#pragma unroll
  for (int i = 0; i < 4; i++) { s += v[i]; ss += v[i] * v[i]; }
  s = wsum(s);
  ss = wsum(ss);
  __shared__ float red[8];
  int wid = t >> 6;
  if ((t & 63) == 0) { red[wid] = s; red[4 + wid] = ss; }
  __syncthreads();
  s = red[0] + red[1] + red[2] + red[3];
  ss = red[4] + red[5] + red[6] + red[7];
  float mean = s * (1.f / 1024.f);
  float var = ss * (1.f / 1024.f) - mean * mean;
  float inv = rsqrtf(var + 1e-5f);
  float4 gv = *(const float4*)(g + t * 4);
  float4 bv = *(const float4*)(bta + t * 4);
  float gg[4] = {gv.x, gv.y, gv.z, gv.w};
  float bb[4] = {bv.x, bv.y, bv.z, bv.w};
  u16 outr[4];
#pragma unroll
  for (int i = 0; i < 4; i++) outr[i] = f2b((v[i] - mean) * inv * gg[i] + bb[i]);
  *(uint2*)(y + base + t * 4) = *(uint2*)outr;
}

// ---------------- fp32 -> bf16 cast ----------------
__global__ __launch_bounds__(256) void cast_kernel(const float* __restrict__ x,
                                                   u16* __restrict__ y) {
  long i = ((long)blockIdx.x * 256 + threadIdx.x) * 4;
  float4 f = *(const float4*)(x + i);
  u16 h[4] = {f2b(f.x), f2b(f.y), f2b(f.z), f2b(f.w)};
  *(uint2*)(y + i) = *(uint2*)h;
}

// ---------------- 1024x1024 transpose, fp32 -> bf16 ----------------
__global__ __launch_bounds__(256) void transpose_w(const float* __restrict__ src,
                                                   u16* __restrict__ dst) {
  __shared__ u16 tile[32][33];
  int tx = threadIdx.x & 31, ty = threadIdx.x >> 5;
  int x = blockIdx.x * 32 + tx;
  int y0 = blockIdx.y * 32;
#pragma unroll
  for (int i = 0; i < 32; i += 8) tile[ty + i][tx] = f2b(src[(long)(y0 + ty + i) * 1024 + x]);
  __syncthreads();
  int X = blockIdx.y * 32 + tx;
  int Y0 = blockIdx.x * 32;
#pragma unroll
  for (int i = 0; i < 32; i += 8) dst[(long)(Y0 + ty + i) * 1024 + X] = tile[tx][ty + i];
}

// ------- per-(b,h) transpose of vp[b,c,h*64+dh] (bf16) -> vT[(b*16+h), dh, c] -------
__global__ __launch_bounds__(256) void transpose_v(const u16* __restrict__ vp,
                                                   u16* __restrict__ vT) {
  int z = blockIdx.z;
  const u16* src = vp + (long)(z >> 4) * 1048576 + (long)(z & 15) * 64;
  u16* dst = vT + (long)z * 65536;
  __shared__ u16 tile[32][33];
  int tx = threadIdx.x & 31, ty = threadIdx.x >> 5;
  int c0 = blockIdx.x * 32, d0 = blockIdx.y * 32;
#pragma unroll
  for (int i = 0; i < 32; i += 8) tile[ty + i][tx] = src[(long)(c0 + ty + i) * 1024 + d0 + tx];
  __syncthreads();
#pragma unroll
  for (int i = 0; i < 32; i += 8) dst[(long)(d0 + ty + i) * 1024 + c0 + tx] = tile[tx][ty + i];
}

// ---------------- MFMA GEMM: C[M,N] = A[M,K] * Bt[N,K]^T (+bias) ----------------
// Leading dim 1024 elements everywhere. A is fp32 (converted during staging) or
// bf16; B is bf16; C is fp32 or bf16. fp32 accumulate. Batched via blockIdx.z
// with (z>>4, z&15) stride decomposition.
template <int BM, int BN, typename TA, typename TC>
__global__ __launch_bounds__(256) void gemm_bt(const TA* __restrict__ A,
                                               const u16* __restrict__ Bt,
                                               const float* __restrict__ bias,
                                               TC* __restrict__ C, int K,
                                               long sAb, long sAh, long sBb, long sBh,
                                               long sCb, long sCh) {
  constexpr int TM = BM / 32;
  constexpr int TN = BN / 32;
  int z = blockIdx.z;
  const TA* Ab = A + (long)(z >> 4) * sAb + (long)(z & 15) * sAh;
  const u16* Bb = Bt + (long)(z >> 4) * sBb + (long)(z & 15) * sBh;
  TC* Cb = C + (long)(z >> 4) * sCb + (long)(z & 15) * sCh;
  long m0 = (long)blockIdx.x * BM;
  long n0 = (long)blockIdx.y * BN;

  __shared__ __align__(16) u16 lsA[BM * 32];
  __shared__ __align__(16) u16 lsB[BN * 32];

  int tid = threadIdx.x;
  int wid = tid >> 6;
  int lane = tid & 63;
  int wm = (wid >> 1) * (BM / 2);
  int wn = (wid & 1) * (BN / 2);
  int lm = lane & 15;
  int quad = lane >> 4;

  f32x4 acc[TM][TN];
#pragma unroll
  for (int i = 0; i < TM; i++)
#pragma unroll
    for (int j = 0; j < TN; j++) acc[i][j] = (f32x4){0.f, 0.f, 0.f, 0.f};

  for (int k0 = 0; k0 < K; k0 += 32) {
    if constexpr (sizeof(TA) == 2) {
      // bf16 A: 8-elem (16B) chunks
#pragma unroll
      for (int c = tid; c < BM * 4; c += 256) {
        int row = c >> 2, col = (c & 3) * 8;
        *(uint4*)&lsA[c * 8] = *(const uint4*)(Ab + (long)(m0 + row) * 1024 + k0 + col);
      }
    } else {
      // fp32 A: 4-elem (16B) chunks, convert to bf16 into LDS
#pragma unroll
      for (int c = tid; c < BM * 8; c += 256) {
        int row = c >> 3, col = (c & 7) * 4;
        float4 f = *(const float4*)(Ab + (long)(m0 + row) * 1024 + k0 + col);
        u16 h[4] = {f2b(f.x), f2b(f.y), f2b(f.z), f2b(f.w)};
        *(uint2*)&lsA[row * 32 + col] = *(uint2*)h;
      }
    }
#pragma unroll
    for (int c = tid; c < BN * 4; c += 256) {
      int row = c >> 2, col = (c & 3) * 8;
      *(uint4*)&lsB[c * 8] = *(const uint4*)(Bb + (long)(n0 + row) * 1024 + k0 + col);
    }
    __syncthreads();
    bf16x8 af[TM], bfr[TN];
#pragma unroll
    for (int i = 0; i < TM; i++)
      af[i] = *(const bf16x8*)&lsA[(wm + i * 16 + lm) * 32 + quad * 8];
#pragma unroll
    for (int j = 0; j < TN; j++)
      bfr[j] = *(const bf16x8*)&lsB[(wn + j * 16 + lm) * 32 + quad * 8];
#pragma unroll
    for (int i = 0; i < TM; i++)
#pragma unroll
      for (int j = 0; j < TN; j++)
        acc[i][j] = __builtin_amdgcn_mfma_f32_16x16x32_bf16(af[i], bfr[j], acc[i][j], 0, 0, 0);
    __syncthreads();
  }

  // epilogue: C/D layout col=lane&15, row=quad*4+reg (m89/m91-verified)
#pragma unroll
  for (int j = 0; j < TN; j++) {
    long n = n0 + wn + j * 16 + lm;
    float bv = bias ? bias[n] : 0.f;
#pragma unroll
    for (int i = 0; i < TM; i++) {
      long mb = m0 + wm + i * 16 + quad * 4;
#pragma unroll
      for (int r = 0; r < 4; r++) {
        float val = acc[i][j][r] + bv;
        if constexpr (sizeof(TC) == 2) Cb[(mb + r) * 1024 + n] = f2b(val);
        else Cb[(mb + r) * 1024 + n] = val;
      }
    }
  }
}

// ---------------- softmax(gelu(s)*0.125) over 1024-elem row, fp32 in place ----------------
__global__ __launch_bounds__(256) void softmax_kernel(float* __restrict__ attn) {
  long base = (long)blockIdx.x * 1024;
  int t = threadIdx.x;
  float4 raw = *(const float4*)(attn + base + t * 4);
  float xin[4] = {raw.x, raw.y, raw.z, raw.w};
  float l[4];
  float mx = -1e30f;
#pragma unroll
  for (int i = 0; i < 4; i++) {
    float x = xin[i];
    float gl = 0.5f * x * (1.f + erff(x * 0.70710678118654752f));
    l[i] = gl * 0.125f;  // Dh^-0.5 = 0.125, applied AFTER gelu
    mx = fmaxf(mx, l[i]);
  }
  mx = wmax(mx);
  __shared__ float redm[4], reds[4];
  int wid = t >> 6;
  if ((t & 63) == 0) redm[wid] = mx;
  __syncthreads();
  mx = fmaxf(fmaxf(redm[0], redm[1]), fmaxf(redm[2], redm[3]));
  float e[4];
  float s = 0.f;
#pragma unroll
  for (int i = 0; i < 4; i++) {
    e[i] = __expf(l[i] - mx);
    s += e[i];
  }
  s = wsum(s);
  if ((t & 63) == 0) reds[wid] = s;
  __syncthreads();
  s = reds[0] + reds[1] + reds[2] + reds[3];
  float inv = 1.f / s;
  float4 outr = {e[0] * inv, e[1] * inv, e[2] * inv, e[3] * inv};
  *(float4*)(attn + base + t * 4) = outr;
}

// ---------------- row-wise L2 normalize (fp32) ----------------
__global__ __launch_bounds__(256) void l2norm_kernel(const float* __restrict__ o,
                                                     float* __restrict__ out) {
  long base = (long)blockIdx.x * 1024;
  int t = threadIdx.x;
  float4 raw = *(const float4*)(o + base + t * 4);
  float v[4] = {raw.x, raw.y, raw.z, raw.w};
  float ss = 0.f;
#pragma unroll
  for (int i = 0; i < 4; i++) ss += v[i] * v[i];
  ss = wsum(ss);
  __shared__ float red[4];
  int wid = t >> 6;
  if ((t & 63) == 0) red[wid] = ss;
  __syncthreads();
  ss = red[0] + red[1] + red[2] + red[3];
  float inv = 1.f / fmaxf(sqrtf(ss), 1e-12f);
  float4 outr = {v[0] * inv, v[1] * inv, v[2] * inv, v[3] * inv};
  *(float4*)(out + base + t * 4) = outr;
}

extern "C" void kernel_launch(void* const* d_in, const int* in_sizes, int n_in,
                              void* d_out, int out_size, void* d_ws, size_t ws_size,
                              hipStream_t stream) {
  const float* q = (const float*)d_in[0];
  const float* k = (const float*)d_in[1];
  const float* v = (const float*)d_in[2];
  const float* ln_k_g = (const float*)d_in[3];
  const float* ln_k_b = (const float*)d_in[4];
  const float* ln_v_g = (const float*)d_in[5];
  const float* ln_v_b = (const float*)d_in[6];
  const float* Wq = (const float*)d_in[7];
  const float* bq = (const float*)d_in[8];
  const float* Wk = (const float*)d_in[9];
  const float* bk = (const float*)d_in[10];
  const float* Wv = (const float*)d_in[11];
  const float* bv_ = (const float*)d_in[12];
  const float* Wo = (const float*)d_in[13];
  const float* bo = (const float*)d_in[14];

  const long MEG = 1024 * 1024;
  u16* ws16 = (u16*)d_ws;
  // bf16 regions (element counts are u16 elements)
  u16* LNK = ws16;                 // 4M u16 (8MB)   — dead after KP proj → CTX
  u16* LNV = ws16 + 4 * MEG;       // 4M u16         — dead after VP proj
  u16* QB  = ws16 + 8 * MEG;       // 4M u16         — dead after QP proj
  u16* WQT = ws16 + 12 * MEG;      // 1M each
  u16* WKT = ws16 + 13 * MEG;
  u16* WVT = ws16 + 14 * MEG;
  u16* WOT = ws16 + 15 * MEG;
  u16* QP  = ws16 + 16 * MEG;      // dead after scores
  u16* KP  = ws16 + 20 * MEG;      // dead after scores → VT
  u16* VP  = ws16 + 24 * MEG;      // dead after transpose_v  (total 56MB)
  u16* VT  = KP;
  u16* CTX = LNK;
  float* OO = (float*)(ws16 + 4 * MEG);  // 4M fp32 = 16MB over LNV+QB (both dead)

  float* out = (float*)d_out;
  float* attn = out + 4 * MEG;

  // q fp32 -> bf16
  cast_kernel<<<4096, 256, 0, stream>>>(q, QB);
  // LayerNorm k, v (fp32 -> bf16)
  ln_kernel<<<4096, 256, 0, stream>>>(k, ln_k_g, ln_k_b, LNK);
  ln_kernel<<<4096, 256, 0, stream>>>(v, ln_v_g, ln_v_b, LNV);

  // Transpose + cast weights so GEMM B-operand is K-contiguous bf16
  transpose_w<<<dim3(32, 32), 256, 0, stream>>>(Wq, WQT);
  transpose_w<<<dim3(32, 32), 256, 0, stream>>>(Wk, WKT);
  transpose_w<<<dim3(32, 32), 256, 0, stream>>>(Wv, WVT);
  transpose_w<<<dim3(32, 32), 256, 0, stream>>>(Wo, WOT);

  // Projections: [4096,1024] @ W^T + bias -> bf16
  gemm_bt<128, 128, u16, u16><<<dim3(32, 8, 1), 256, 0, stream>>>(
      QB, WQT, bq, QP, 1024, 0, 0, 0, 0, 0, 0);
  gemm_bt<128, 128, u16, u16><<<dim3(32, 8, 1), 256, 0, stream>>>(
      LNK, WKT, bk, KP, 1024, 0, 0, 0, 0, 0, 0);
  gemm_bt<128, 128, u16, u16><<<dim3(32, 8, 1), 256, 0, stream>>>(
      LNV, WVT, bv_, VP, 1024, 0, 0, 0, 0, 0, 0);

  // scores[b,h,c,c'] = qh @ kh^T  (z = b*16+h; K=64) -> fp32 into attn buffer
  gemm_bt<128, 128, u16, float><<<dim3(8, 8, 64), 256, 0, stream>>>(
      QP, KP, nullptr, attn, 64,
      1048576, 64,         // A: b*1M + h*64 into qp
      1048576, 64,         // B: same into kp
      16777216, 1048576);  // C: z*1M into attn (fp32 elements)

  // vT[(b*16+h), dh, c]  (overwrites KP — dead after scores)
  transpose_v<<<dim3(32, 2, 64), 256, 0, stream>>>(VP, VT);

  // softmax(gelu * 0.125) in place over last dim (fp32)
  softmax_kernel<<<65536, 256, 0, stream>>>(attn);

  // ctx[b,c,h*64+dh] = attn @ vh   (M=1024, N=64, K=1024 per z) -> bf16
  gemm_bt<128, 64, float, u16><<<dim3(8, 1, 64), 256, 0, stream>>>(
      attn, VT, nullptr, CTX, 1024,
      16777216, 1048576,  // A: z*1M (fp32) into attn
      1048576, 65536,     // B: z*64K into vT
      1048576, 64);       // C: b*1M + h*64 into ctx

  // output projection + bias -> fp32
  gemm_bt<128, 128, u16, float><<<dim3(32, 8, 1), 256, 0, stream>>>(
      CTX, WOT, bo, OO, 1024, 0, 0, 0, 0, 0, 0);

  // L2 normalize rows -> out
  l2norm_kernel<<<4096, 256, 0, stream>>>(OO, out);
}

// Round 3
// 678.175 us; speedup vs baseline: 1.1369x; 1.1369x over previous
//
#include <hip/hip_runtime.h>

typedef unsigned short u16;
typedef __attribute__((ext_vector_type(8))) short bf16x8;
typedef __attribute__((ext_vector_type(4))) float f32x4;

__device__ inline float b2f(u16 u) {
  unsigned x = ((unsigned)u) << 16;
  return __uint_as_float(x);
}
__device__ inline u16 f2b(float f) {
  unsigned u = __float_as_uint(f);
  unsigned r = (u + 0x7fffu + ((u >> 16) & 1u)) >> 16;
  return (u16)r;
}

__device__ inline float wsum(float x) {
#pragma unroll
  for (int o = 32; o > 0; o >>= 1) x += __shfl_down(x, o);
  return x;
}

// ---------------- LayerNorm fp32 -> bf16 (one block per 1024-elem row) ----------------
__global__ __launch_bounds__(256) void ln_kernel(const float* __restrict__ x,
                                                 const float* __restrict__ g,
                                                 const float* __restrict__ bta,
                                                 u16* __restrict__ y) {
  long base = (long)blockIdx.x * 1024;
  int t = threadIdx.x;
  float4 raw = *(const float4*)(x + base + t * 4);
  float v[4] = {raw.x, raw.y, raw.z, raw.w};
  float s = 0.f, ss = 0.f;
#pragma unroll
  for (int i = 0; i < 4; i++) { s += v[i]; ss += v[i] * v[i]; }
  s = wsum(s);
  ss = wsum(ss);
  __shared__ float red[8];
  int wid = t >> 6;
  if ((t & 63) == 0) { red[wid] = s; red[4 + wid] = ss; }
  __syncthreads();
  s = red[0] + red[1] + red[2] + red[3];
  ss = red[4] + red[5] + red[6] + red[7];
  float mean = s * (1.f / 1024.f);
  float var = ss * (1.f / 1024.f) - mean * mean;
  float inv = rsqrtf(var + 1e-5f);
  float4 gv = *(const float4*)(g + t * 4);
  float4 bv = *(const float4*)(bta + t * 4);
  float gg[4] = {gv.x, gv.y, gv.z, gv.w};
  float bb[4] = {bv.x, bv.y, bv.z, bv.w};
  u16 outr[4];
#pragma unroll
  for (int i = 0; i < 4; i++) outr[i] = f2b((v[i] - mean) * inv * gg[i] + bb[i]);
  *(uint2*)(y + base + t * 4) = *(uint2*)outr;
}

// ---------------- 1024x1024 transpose, fp32 -> bf16 ----------------
__global__ __launch_bounds__(256) void transpose_w(const float* __restrict__ src,
                                                   u16* __restrict__ dst) {
  __shared__ u16 tile[32][33];
  int tx = threadIdx.x & 31, ty = threadIdx.x >> 5;
  int x = blockIdx.x * 32 + tx;
  int y0 = blockIdx.y * 32;
#pragma unroll
  for (int i = 0; i < 32; i += 8) tile[ty + i][tx] = f2b(src[(long)(y0 + ty + i) * 1024 + x]);
  __syncthreads();
  int X = blockIdx.y * 32 + tx;
  int Y0 = blockIdx.x * 32;
#pragma unroll
  for (int i = 0; i < 32; i += 8) dst[(long)(Y0 + ty + i) * 1024 + X] = tile[tx][ty + i];
}

// ------- per-(b,h) transpose of vp[b,c,h*64+dh] (bf16) -> vT[(b*16+h), dh, c] -------
__global__ __launch_bounds__(256) void transpose_v(const u16* __restrict__ vp,
                                                   u16* __restrict__ vT) {
  int z = blockIdx.z;
  const u16* src = vp + (long)(z >> 4) * 1048576 + (long)(z & 15) * 64;
  u16* dst = vT + (long)z * 65536;
  __shared__ u16 tile[32][33];
  int tx = threadIdx.x & 31, ty = threadIdx.x >> 5;
  int c0 = blockIdx.x * 32, d0 = blockIdx.y * 32;
#pragma unroll
  for (int i = 0; i < 32; i += 8) tile[ty + i][tx] = src[(long)(c0 + ty + i) * 1024 + d0 + tx];
  __syncthreads();
#pragma unroll
  for (int i = 0; i < 32; i += 8) dst[(long)(d0 + ty + i) * 1024 + c0 + tx] = tile[tx][ty + i];
}

// ---------------- MFMA GEMM: C[M,N] = A[M,K] * Bt[N,K]^T (+bias) ----------------
template <int BM, int BN, typename TA, typename TC>
__global__ __launch_bounds__(256) void gemm_bt(const TA* __restrict__ A,
                                               const u16* __restrict__ Bt,
                                               const float* __restrict__ bias,
                                               TC* __restrict__ C, int K,
                                               long sAb, long sAh, long sBb, long sBh,
                                               long sCb, long sCh) {
  constexpr int TM = BM / 32;
  constexpr int TN = BN / 32;
  int z = blockIdx.z;
  const TA* Ab = A + (long)(z >> 4) * sAb + (long)(z & 15) * sAh;
  const u16* Bb = Bt + (long)(z >> 4) * sBb + (long)(z & 15) * sBh;
  TC* Cb = C + (long)(z >> 4) * sCb + (long)(z & 15) * sCh;
  long m0 = (long)blockIdx.x * BM;
  long n0 = (long)blockIdx.y * BN;

  __shared__ __align__(16) u16 lsA[BM * 32];
  __shared__ __align__(16) u16 lsB[BN * 32];

  int tid = threadIdx.x;
  int wid = tid >> 6;
  int lane = tid & 63;
  int wm = (wid >> 1) * (BM / 2);
  int wn = (wid & 1) * (BN / 2);
  int lm = lane & 15;
  int quad = lane >> 4;

  f32x4 acc[TM][TN];
#pragma unroll
  for (int i = 0; i < TM; i++)
#pragma unroll
    for (int j = 0; j < TN; j++) acc[i][j] = (f32x4){0.f, 0.f, 0.f, 0.f};

  for (int k0 = 0; k0 < K; k0 += 32) {
    if constexpr (sizeof(TA) == 2) {
#pragma unroll
      for (int c = tid; c < BM * 4; c += 256) {
        int row = c >> 2, col = (c & 3) * 8;
        *(uint4*)&lsA[c * 8] = *(const uint4*)(Ab + (long)(m0 + row) * 1024 + k0 + col);
      }
    } else {
#pragma unroll
      for (int c = tid; c < BM * 8; c += 256) {
        int row = c >> 3, col = (c & 7) * 4;
        float4 f = *(const float4*)(Ab + (long)(m0 + row) * 1024 + k0 + col);
        u16 h[4] = {f2b(f.x), f2b(f.y), f2b(f.z), f2b(f.w)};
        *(uint2*)&lsA[row * 32 + col] = *(uint2*)h;
      }
    }
#pragma unroll
    for (int c = tid; c < BN * 4; c += 256) {
      int row = c >> 2, col = (c & 3) * 8;
      *(uint4*)&lsB[c * 8] = *(const uint4*)(Bb + (long)(n0 + row) * 1024 + k0 + col);
    }
    __syncthreads();
    bf16x8 af[TM], bfr[TN];
#pragma unroll
    for (int i = 0; i < TM; i++)
      af[i] = *(const bf16x8*)&lsA[(wm + i * 16 + lm) * 32 + quad * 8];
#pragma unroll
    for (int j = 0; j < TN; j++)
      bfr[j] = *(const bf16x8*)&lsB[(wn + j * 16 + lm) * 32 + quad * 8];
#pragma unroll
    for (int i = 0; i < TM; i++)
#pragma unroll
      for (int j = 0; j < TN; j++)
        acc[i][j] = __builtin_amdgcn_mfma_f32_16x16x32_bf16(af[i], bfr[j], acc[i][j], 0, 0, 0);
    __syncthreads();
  }

#pragma unroll
  for (int j = 0; j < TN; j++) {
    long n = n0 + wn + j * 16 + lm;
    float bv = bias ? bias[n] : 0.f;
#pragma unroll
    for (int i = 0; i < TM; i++) {
      long mb = m0 + wm + i * 16 + quad * 4;
#pragma unroll
      for (int r = 0; r < 4; r++) {
        float val = acc[i][j][r] + bv;
        if constexpr (sizeof(TC) == 2) Cb[(mb + r) * 1024 + n] = f2b(val);
        else Cb[(mb + r) * 1024 + n] = val;
      }
    }
  }
}

// ---------------- fused attention: scores + gelu + softmax + attn write + P·V ----------------
// grid (64 q-tiles, 64 z). One block: 16 Q-rows x full 1024 keys.
// QP/KP: bf16 [b][c][h*64+dh] ld 1024. VT: bf16 [z][dh][c'] ld 1024.
// attn: fp32 [z][c][c']. CTX: bf16 [b][c][h*64+dh].
__global__ __launch_bounds__(256) void fused_attn(const u16* __restrict__ QP,
                                                  const u16* __restrict__ KP,
                                                  const u16* __restrict__ VT,
                                                  float* __restrict__ attn,
                                                  u16* __restrict__ CTX) {
  __shared__ __align__(16) u16 lgt[16 * 1032];  // logits then P (bf16); stride 1032: 2-way free
  __shared__ __align__(16) u16 qt[16 * 72];
  __shared__ float rowm[16], rowinv[16];

  int z = blockIdx.y;
  int b = z >> 4, h = z & 15;
  long q0 = (long)blockIdx.x * 16;
  int tid = threadIdx.x;
  int wid = tid >> 6, lane = tid & 63;
  int lm = lane & 15, quad = lane >> 4;

  const u16* Qb = QP + (long)b * 1048576 + (long)h * 64;
  const u16* Kb = KP + (long)b * 1048576 + (long)h * 64;
  const u16* Vz = VT + (long)z * 65536;
  float* Az = attn + (long)z * 1048576;

  // stage Q tile 16x64 (bf16)
  if (tid < 128) {
    int row = tid >> 3, col8 = (tid & 7) * 8;
    *(uint4*)&qt[row * 72 + col8] = *(const uint4*)(Qb + (q0 + row) * 1024 + col8);
  }
  __syncthreads();

  // ---- scores: wave wid computes cols [wid*256, wid*256+256) ----
  bf16x8 af0 = *(const bf16x8*)&qt[lm * 72 + quad * 8];
  bf16x8 af1 = *(const bf16x8*)&qt[lm * 72 + 32 + quad * 8];
  {
    int ncol0 = wid * 256;
#pragma unroll 4
    for (int jj = 0; jj < 16; jj++) {
      int n = ncol0 + jj * 16 + lm;
      const u16* kr = Kb + (long)n * 1024;
      bf16x8 bf0 = *(const bf16x8*)(kr + quad * 8);
      bf16x8 bf1 = *(const bf16x8*)(kr + 32 + quad * 8);
      f32x4 s = (f32x4){0.f, 0.f, 0.f, 0.f};
      s = __builtin_amdgcn_mfma_f32_16x16x32_bf16(af0, bf0, s, 0, 0, 0);
      s = __builtin_amdgcn_mfma_f32_16x16x32_bf16(af1, bf1, s, 0, 0, 0);
#pragma unroll
      for (int r = 0; r < 4; r++) {
        float x = s[r];
        float gl = 0.5f * x * (1.f + erff(x * 0.70710678118654752f));
        lgt[(quad * 4 + r) * 1032 + n] = f2b(gl * 0.125f);
      }
    }
  }
  __syncthreads();

  // ---- row max (16 threads per row, 64 cols each) ----
  int rr = tid >> 4, seg = tid & 15;
  {
    const u16* p = &lgt[rr * 1032 + seg * 64];
    float mx = -1e30f;
#pragma unroll
    for (int i = 0; i < 16; i++) {
      uint2 raw = *(const uint2*)(p + i * 4);
      u16* pr = (u16*)&raw;
      mx = fmaxf(fmaxf(fmaxf(b2f(pr[0]), b2f(pr[1])), fmaxf(b2f(pr[2]), b2f(pr[3]))), mx);
    }
#pragma unroll
    for (int d = 8; d > 0; d >>= 1) mx = fmaxf(mx, __shfl_down(mx, d));
    if (seg == 0) rowm[rr] = mx;
  }
  __syncthreads();
  // ---- row sum of exp ----
  {
    float m = rowm[rr];
    const u16* p = &lgt[rr * 1032 + seg * 64];
    float s = 0.f;
#pragma unroll
    for (int i = 0; i < 16; i++) {
      uint2 raw = *(const uint2*)(p + i * 4);
      u16* pr = (u16*)&raw;
      s += __expf(b2f(pr[0]) - m) + __expf(b2f(pr[1]) - m) +
           __expf(b2f(pr[2]) - m) + __expf(b2f(pr[3]) - m);
    }
#pragma unroll
    for (int d = 8; d > 0; d >>= 1) s += __shfl_down(s, d);
    if (seg == 0) rowinv[rr] = 1.f / s;
  }
  __syncthreads();

  // ---- normalize in place (thread t owns cols 4t..4t+3 of every row) + attn write ----
#pragma unroll
  for (int r = 0; r < 16; r++) {
    float m = rowm[r], inv = rowinv[r];
    uint2 raw = *(const uint2*)&lgt[r * 1032 + tid * 4];
    u16* pr = (u16*)&raw;
    float4 o;
    u16 pk[4];
    float e0 = __expf(b2f(pr[0]) - m) * inv;
    float e1 = __expf(b2f(pr[1]) - m) * inv;
    float e2 = __expf(b2f(pr[2]) - m) * inv;
    float e3 = __expf(b2f(pr[3]) - m) * inv;
    o.x = e0; o.y = e1; o.z = e2; o.w = e3;
    pk[0] = f2b(e0); pk[1] = f2b(e1); pk[2] = f2b(e2); pk[3] = f2b(e3);
    *(float4*)(Az + (q0 + r) * 1024 + tid * 4) = o;
    *(uint2*)&lgt[r * 1032 + tid * 4] = *(uint2*)pk;
  }
  __syncthreads();

  // ---- P·V: wave wid owns dh tile [wid*16, wid*16+16) ----
  {
    f32x4 acc = (f32x4){0.f, 0.f, 0.f, 0.f};
    const u16* Vrow = Vz + (long)(wid * 16 + lm) * 1024;
#pragma unroll 4
    for (int kc = 0; kc < 1024; kc += 32) {
      bf16x8 a = *(const bf16x8*)&lgt[lm * 1032 + kc + quad * 8];
      bf16x8 bv = *(const bf16x8*)(Vrow + kc + quad * 8);
      acc = __builtin_amdgcn_mfma_f32_16x16x32_bf16(a, bv, acc, 0, 0, 0);
    }
    int n = wid * 16 + lm;
    u16* Cb = CTX + (long)b * 1048576 + (long)h * 64;
#pragma unroll
    for (int r = 0; r < 4; r++) {
      Cb[(q0 + quad * 4 + r) * 1024 + n] = f2b(acc[r]);
    }
  }
}

// ---------------- row-wise L2 normalize (fp32) ----------------
__global__ __launch_bounds__(256) void l2norm_kernel(const float* __restrict__ o,
                                                     float* __restrict__ out) {
  long base = (long)blockIdx.x * 1024;
  int t = threadIdx.x;
  float4 raw = *(const float4*)(o + base + t * 4);
  float v[4] = {raw.x, raw.y, raw.z, raw.w};
  float ss = 0.f;
#pragma unroll
  for (int i = 0; i < 4; i++) ss += v[i] * v[i];
  ss = wsum(ss);
  __shared__ float red[4];
  int wid = t >> 6;
  if ((t & 63) == 0) red[wid] = ss;
  __syncthreads();
  ss = red[0] + red[1] + red[2] + red[3];
  float inv = 1.f / fmaxf(sqrtf(ss), 1e-12f);
  float4 outr = {v[0] * inv, v[1] * inv, v[2] * inv, v[3] * inv};
  *(float4*)(out + base + t * 4) = outr;
}

extern "C" void kernel_launch(void* const* d_in, const int* in_sizes, int n_in,
                              void* d_out, int out_size, void* d_ws, size_t ws_size,
                              hipStream_t stream) {
  const float* q = (const float*)d_in[0];
  const float* k = (const float*)d_in[1];
  const float* v = (const float*)d_in[2];
  const float* ln_k_g = (const float*)d_in[3];
  const float* ln_k_b = (const float*)d_in[4];
  const float* ln_v_g = (const float*)d_in[5];
  const float* ln_v_b = (const float*)d_in[6];
  const float* Wq = (const float*)d_in[7];
  const float* bq = (const float*)d_in[8];
  const float* Wk = (const float*)d_in[9];
  const float* bk = (const float*)d_in[10];
  const float* Wv = (const float*)d_in[11];
  const float* bv_ = (const float*)d_in[12];
  const float* Wo = (const float*)d_in[13];
  const float* bo = (const float*)d_in[14];

  const long MEG = 1024 * 1024;
  u16* ws16 = (u16*)d_ws;
  u16* LNK = ws16;                 // 0..4M u16; dead after k-proj -> CTX
  u16* LNV = ws16 + 4 * MEG;       // dead after v-proj
  u16* WQT = ws16 + 8 * MEG;
  u16* WKT = ws16 + 9 * MEG;
  u16* WVT = ws16 + 10 * MEG;
  u16* WOT = ws16 + 11 * MEG;      // alive until final proj
  u16* QP  = ws16 + 12 * MEG;      // dead after fused -> OO (fp32, 16MB: 12M..20M u16)
  u16* KP  = ws16 + 16 * MEG;      // dead after fused
  u16* VP  = ws16 + 20 * MEG;      // dead after transpose_v
  u16* VT  = ws16 + 24 * MEG;      // alive through fused (56 MB total)
  u16* CTX = LNK;
  float* OO = (float*)(ws16 + 12 * MEG);

  float* out = (float*)d_out;
  float* attn = out + 4 * MEG;

  ln_kernel<<<4096, 256, 0, stream>>>(k, ln_k_g, ln_k_b, LNK);
  ln_kernel<<<4096, 256, 0, stream>>>(v, ln_v_g, ln_v_b, LNV);

  transpose_w<<<dim3(32, 32), 256, 0, stream>>>(Wq, WQT);
  transpose_w<<<dim3(32, 32), 256, 0, stream>>>(Wk, WKT);
  transpose_w<<<dim3(32, 32), 256, 0, stream>>>(Wv, WVT);
  transpose_w<<<dim3(32, 32), 256, 0, stream>>>(Wo, WOT);

  // Projections (q is fp32 A, converted during staging)
  gemm_bt<128, 128, float, u16><<<dim3(32, 8, 1), 256, 0, stream>>>(
      q, WQT, bq, QP, 1024, 0, 0, 0, 0, 0, 0);
  gemm_bt<128, 128, u16, u16><<<dim3(32, 8, 1), 256, 0, stream>>>(
      LNK, WKT, bk, KP, 1024, 0, 0, 0, 0, 0, 0);
  gemm_bt<128, 128, u16, u16><<<dim3(32, 8, 1), 256, 0, stream>>>(
      LNV, WVT, bv_, VP, 1024, 0, 0, 0, 0, 0, 0);

  transpose_v<<<dim3(32, 2, 64), 256, 0, stream>>>(VP, VT);

  // fused scores+gelu+softmax+attn+PV
  fused_attn<<<dim3(64, 64), 256, 0, stream>>>(QP, KP, VT, attn, CTX);

  // output projection + bias -> fp32
  gemm_bt<128, 128, u16, float><<<dim3(32, 8, 1), 256, 0, stream>>>(
      CTX, WOT, bo, OO, 1024, 0, 0, 0, 0, 0, 0);

  l2norm_kernel<<<4096, 256, 0, stream>>>(OO, out);
}